// Round 1
// baseline (820.065 us; speedup 1.0000x reference)
//
#include <hip/hip_runtime.h>
#include <hip/hip_bf16.h>
#include <float.h>
#include <math.h>

// dims
#define BB   4
#define SS   16
#define TQN  2048
#define DD   768
#define NTT  64
#define NKK  1024     // SS*NTT
#define MID1 204
#define MID2 409

// ---------------------------------------------------------------------------
// K1: test = mean over s of test_reps  (the HBM-bound pass: 403 MB read)
// ---------------------------------------------------------------------------
__global__ __launch_bounds__(256) void k_mean(const float4* __restrict__ reps,
                                              float4* __restrict__ testM) {
    const int QD4 = TQN * DD / 4;                 // 393216 float4 per (b, s)
    int id = blockIdx.x * 256 + threadIdx.x;      // [0, BB*QD4)
    int b = id / QD4, rem = id - b * QD4;
    const float4* base = reps + (size_t)b * SS * QD4 + rem;
    float4 acc = {0.f, 0.f, 0.f, 0.f};
#pragma unroll
    for (int s = 0; s < SS; ++s) {
        float4 v = base[(size_t)s * QD4];
        acc.x += v.x; acc.y += v.y; acc.z += v.z; acc.w += v.w;
    }
    const float inv = 1.f / SS;
    acc.x *= inv; acc.y *= inv; acc.z *= inv; acc.w *= inv;
    testM[(size_t)b * QD4 + rem] = acc;
}

// ---------------------------------------------------------------------------
// K2: U[b,s,q] = support_reps[b,s,:] . testM[b,q,:]
// ---------------------------------------------------------------------------
__global__ __launch_bounds__(192) void k_u(const float4* __restrict__ testM,
                                           const float4* __restrict__ sup,
                                           float* __restrict__ U) {
    int b = blockIdx.x / TQN, q = blockIdx.x % TQN;
    int t = threadIdx.x;                          // 0..191, each owns 4 d's
    float4 tv = testM[((size_t)b * TQN + q) * (DD / 4) + t];
    float part[SS];
#pragma unroll
    for (int s = 0; s < SS; ++s) {
        float4 sv = sup[((size_t)b * SS + s) * (DD / 4) + t];
        part[s] = tv.x * sv.x + tv.y * sv.y + tv.z * sv.z + tv.w * sv.w;
    }
    __shared__ float rbuf[3][SS];
    int lane = t & 63, wv = t >> 6;
#pragma unroll
    for (int s = 0; s < SS; ++s) {
        float v = part[s];
        for (int o = 32; o; o >>= 1) v += __shfl_down(v, o, 64);
        if (lane == 0) rbuf[wv][s] = v;
    }
    __syncthreads();
    if (t < SS)
        U[((size_t)b * SS + t) * TQN + q] = rbuf[0][t] + rbuf[1][t] + rbuf[2][t];
}

// ---------------------------------------------------------------------------
// K3: per-(b,s) stats of U over q, and of tgt over n
// ---------------------------------------------------------------------------
__global__ __launch_bounds__(256) void k_stats(const float* __restrict__ U,
                                               const float* __restrict__ tgt,
                                               float* __restrict__ Umax, float* __restrict__ Umin,
                                               float* __restrict__ Usum,
                                               float* __restrict__ cmax, float* __restrict__ cmin,
                                               float* __restrict__ csum) {
    int bs = blockIdx.x, t = threadIdx.x;
    const float* u = U + (size_t)bs * TQN;
    float mx = -FLT_MAX, mn = FLT_MAX, sm = 0.f;
    for (int q = t; q < TQN; q += 256) {
        float v = u[q];
        mx = fmaxf(mx, v); mn = fminf(mn, v); sm += v;
    }
    int lane = t & 63, wv = t >> 6;
    for (int o = 32; o; o >>= 1) {
        mx = fmaxf(mx, __shfl_down(mx, o, 64));
        mn = fminf(mn, __shfl_down(mn, o, 64));
        sm += __shfl_down(sm, o, 64);
    }
    __shared__ float smx[4], smn[4], ssm[4];
    if (lane == 0) { smx[wv] = mx; smn[wv] = mn; ssm[wv] = sm; }
    __syncthreads();
    if (t == 0) {
        Umax[bs] = fmaxf(fmaxf(smx[0], smx[1]), fmaxf(smx[2], smx[3]));
        Umin[bs] = fminf(fminf(smn[0], smn[1]), fminf(smn[2], smn[3]));
        Usum[bs] = ssm[0] + ssm[1] + ssm[2] + ssm[3];
    }
    if (wv == 1) {  // wave 1 handles the 64 tgt values
        float v = tgt[(size_t)bs * NTT + lane];
        float tmx = v, tmn = v, tsm = v;
        for (int o = 32; o; o >>= 1) {
            tmx = fmaxf(tmx, __shfl_down(tmx, o, 64));
            tmn = fminf(tmn, __shfl_down(tmn, o, 64));
            tsm += __shfl_down(tsm, o, 64);
        }
        if (lane == 0) { cmax[bs] = tmx; cmin[bs] = tmn; csum[bs] = tsm; }
    }
}

// ---------------------------------------------------------------------------
// K4: branch-1 row features: xmax/xmean over q for each support row
// ---------------------------------------------------------------------------
__global__ __launch_bounds__(256) void k_rowfeat(const float* __restrict__ tgt,
                                                 const float* __restrict__ Umax,
                                                 const float* __restrict__ Umin,
                                                 const float* __restrict__ Usum,
                                                 float* __restrict__ xmax, float* __restrict__ xmean) {
    int i = blockIdx.x * 256 + threadIdx.x;  // [0, BB*NKK)
    int b = i >> 10, r = i & 1023, s = r >> 6;
    int bs = b * SS + s;
    float c = tgt[i];  // flat (b*16+s)*64+n == i
    xmax[i]  = c > 0.f ? c * Umax[bs] : (c < 0.f ? c * Umin[bs] : 0.f);
    xmean[i] = c * Usum[bs] * (1.f / TQN);
}

// ---------------------------------------------------------------------------
// K5: MLP1 hidden: h1[b][{max,mean}][j] = relu(x . w1[:,j] + b1[j])
// ---------------------------------------------------------------------------
__global__ __launch_bounds__(256) void k_mlp1_h(const float* __restrict__ xmax,
                                                const float* __restrict__ xmean,
                                                const float* __restrict__ w1,
                                                const float* __restrict__ b1,
                                                float* __restrict__ h1) {
    int b = blockIdx.x, t = threadIdx.x;
    __shared__ float sx[NKK], sa[NKK];
    for (int i = t; i < NKK; i += 256) { sx[i] = xmax[b * NKK + i]; sa[i] = xmean[b * NKK + i]; }
    __syncthreads();
    if (t < MID1) {
        float am = b1[t], aa = b1[t];
        for (int r = 0; r < NKK; ++r) {
            float w = w1[r * MID1 + t];
            am += sx[r] * w; aa += sa[r] * w;
        }
        h1[(b * 2 + 0) * MID1 + t] = fmaxf(am, 0.f);
        h1[(b * 2 + 1) * MID1 + t] = fmaxf(aa, 0.f);
    }
}

// ---------------------------------------------------------------------------
// K6: MLP1 out + fuse MLP + softmax(axis=1) + 1  ->  W1 (B,1024)
// ---------------------------------------------------------------------------
__global__ __launch_bounds__(256) void k_w1(const float* __restrict__ h1,
                                            const float* __restrict__ w2,
                                            const float* __restrict__ b2,
                                            const float* __restrict__ fw1, const float* __restrict__ fb1,
                                            const float* __restrict__ fw2, const float* __restrict__ fb2,
                                            float* __restrict__ W1) {
    int b = blockIdx.x, t = threadIdx.x;
    __shared__ float hm[MID1], ha[MID1];
    for (int i = t; i < MID1; i += 256) { hm[i] = h1[(b * 2 + 0) * MID1 + i]; ha[i] = h1[(b * 2 + 1) * MID1 + i]; }
    __syncthreads();
    float y[4];
#pragma unroll
    for (int k = 0; k < 4; ++k) {
        int r = t + 256 * k;
        float ym = b2[r], ya = b2[r];
        for (int j = 0; j < MID1; ++j) {
            float w = w2[j * NKK + r];
            ym += hm[j] * w; ya += ha[j] * w;
        }
        // concat([W1a(mean), W1m(max)]) @ fu_w1 -> relu -> @ fu_w2
        float z = fmaxf(ya * fw1[0] + ym * fw1[1] + fb1[0], 0.f);
        y[k] = z * fw2[0] + fb2[0];
    }
    int lane = t & 63, wv = t >> 6;
    __shared__ float rb[4];
    float mx = fmaxf(fmaxf(y[0], y[1]), fmaxf(y[2], y[3]));
    for (int o = 32; o; o >>= 1) mx = fmaxf(mx, __shfl_down(mx, o, 64));
    if (lane == 0) rb[wv] = mx;
    __syncthreads();
    mx = fmaxf(fmaxf(rb[0], rb[1]), fmaxf(rb[2], rb[3]));
    __syncthreads();
    float e[4], sm = 0.f;
#pragma unroll
    for (int k = 0; k < 4; ++k) { e[k] = expf(y[k] - mx); sm += e[k]; }
    for (int o = 32; o; o >>= 1) sm += __shfl_down(sm, o, 64);
    if (lane == 0) rb[wv] = sm;
    __syncthreads();
    sm = rb[0] + rb[1] + rb[2] + rb[3];
    float inv = 1.f / sm;
#pragma unroll
    for (int k = 0; k < 4; ++k) W1[b * NKK + t + 256 * k] = e[k] * inv + 1.f;
}

// ---------------------------------------------------------------------------
// K7: branch-2 column features over support rows (factored via cmax/cmin/csum)
// ---------------------------------------------------------------------------
__global__ __launch_bounds__(256) void k_colfeat(const float* __restrict__ U,
                                                 const float* __restrict__ cmax,
                                                 const float* __restrict__ cmin,
                                                 const float* __restrict__ csum,
                                                 float* __restrict__ ymax, float* __restrict__ ymean) {
    int i = blockIdx.x * 256 + threadIdx.x;  // [0, BB*TQN)
    int b = i >> 11, q = i & 2047;
    float vmax = -FLT_MAX, vsum = 0.f;
#pragma unroll
    for (int s = 0; s < SS; ++s) {
        int bs = b * SS + s;
        float u = U[(size_t)bs * TQN + q];
        float pm = u > 0.f ? u * cmax[bs] : (u < 0.f ? u * cmin[bs] : 0.f);
        vmax = fmaxf(vmax, pm);
        vsum += u * csum[bs];
    }
    ymax[i] = vmax;
    ymean[i] = vsum * (1.f / NKK);
}

// ---------------------------------------------------------------------------
// K8: MLP2 hidden
// ---------------------------------------------------------------------------
__global__ __launch_bounds__(512) void k_mlp2_h(const float* __restrict__ ymax,
                                                const float* __restrict__ ymean,
                                                const float* __restrict__ w1,
                                                const float* __restrict__ b1,
                                                float* __restrict__ h2) {
    int b = blockIdx.x, t = threadIdx.x;
    __shared__ float sm2[TQN], sa2[TQN];
    for (int i = t; i < TQN; i += 512) { sm2[i] = ymax[b * TQN + i]; sa2[i] = ymean[b * TQN + i]; }
    __syncthreads();
    if (t < MID2) {
        float am = b1[t], aa = b1[t];
        for (int r = 0; r < TQN; ++r) {
            float w = w1[r * MID2 + t];
            am += sm2[r] * w; aa += sa2[r] * w;
        }
        h2[(b * 2 + 0) * MID2 + t] = fmaxf(am, 0.f);
        h2[(b * 2 + 1) * MID2 + t] = fmaxf(aa, 0.f);
    }
}

// ---------------------------------------------------------------------------
// K9: MLP2 out + fuse + softmax + 1 -> W2 (B,2048)
// ---------------------------------------------------------------------------
__global__ __launch_bounds__(256) void k_w2(const float* __restrict__ h2,
                                            const float* __restrict__ w2,
                                            const float* __restrict__ b2,
                                            const float* __restrict__ fw1, const float* __restrict__ fb1,
                                            const float* __restrict__ fw2, const float* __restrict__ fb2,
                                            float* __restrict__ W2) {
    int b = blockIdx.x, t = threadIdx.x;
    __shared__ float hm[MID2], ha[MID2];
    for (int i = t; i < MID2; i += 256) { hm[i] = h2[(b * 2 + 0) * MID2 + i]; ha[i] = h2[(b * 2 + 1) * MID2 + i]; }
    __syncthreads();
    float y[8];
#pragma unroll
    for (int k = 0; k < 8; ++k) {
        int r = t + 256 * k;
        float ym = b2[r], ya = b2[r];
        for (int j = 0; j < MID2; ++j) {
            float w = w2[j * TQN + r];
            ym += hm[j] * w; ya += ha[j] * w;
        }
        float z = fmaxf(ya * fw1[0] + ym * fw1[1] + fb1[0], 0.f);
        y[k] = z * fw2[0] + fb2[0];
    }
    int lane = t & 63, wv = t >> 6;
    __shared__ float rb[4];
    float mx = y[0];
#pragma unroll
    for (int k = 1; k < 8; ++k) mx = fmaxf(mx, y[k]);
    for (int o = 32; o; o >>= 1) mx = fmaxf(mx, __shfl_down(mx, o, 64));
    if (lane == 0) rb[wv] = mx;
    __syncthreads();
    mx = fmaxf(fmaxf(rb[0], rb[1]), fmaxf(rb[2], rb[3]));
    __syncthreads();
    float e[8], sm = 0.f;
#pragma unroll
    for (int k = 0; k < 8; ++k) { e[k] = expf(y[k] - mx); sm += e[k]; }
    for (int o = 32; o; o >>= 1) sm += __shfl_down(sm, o, 64);
    if (lane == 0) rb[wv] = sm;
    __syncthreads();
    sm = rb[0] + rb[1] + rb[2] + rb[3];
    float inv = 1.f / sm;
#pragma unroll
    for (int k = 0; k < 8; ++k) W2[b * TQN + t + 256 * k] = e[k] * inv + 1.f;
}

// ---------------------------------------------------------------------------
// K10: proto[b,n,:] = (sum_s W1[b,s*64+n]*tgt[b,s,n]*sup[b,s,:]) / (count+1e-4)
// ---------------------------------------------------------------------------
__global__ __launch_bounds__(256) void k_proto(const float* __restrict__ W1,
                                               const float* __restrict__ tgt,
                                               const float* __restrict__ sup,
                                               float* __restrict__ proto) {
    int bn = blockIdx.x;           // [0, BB*NTT)
    int b = bn >> 6, n = bn & 63;
    int t = threadIdx.x;
    float a0 = 0.f, a1 = 0.f, a2 = 0.f, cnt = 0.f;
#pragma unroll
    for (int s = 0; s < SS; ++s) {
        float tg = tgt[((size_t)b * SS + s) * NTT + n];
        float coef = W1[b * NKK + s * NTT + n] * tg;
        const float* sv = sup + ((size_t)b * SS + s) * DD;
        a0 += coef * sv[t];
        a1 += coef * sv[t + 256];
        a2 += coef * sv[t + 512];
        cnt += tg;
    }
    float inv = 1.f / (cnt + 1e-4f);
    float* p = proto + (size_t)bn * DD;
    p[t] = a0 * inv; p[t + 256] = a1 * inv; p[t + 512] = a2 * inv;
}

// ---------------------------------------------------------------------------
// K11: sim[b,q,n] = W2[b,q] * (testM[b,q,:] . proto[b,n,:])
//      blocks: (b, 32-q tile) x all 64 n; LDS tiled, +1 row pad (2-way = free)
// ---------------------------------------------------------------------------
__global__ __launch_bounds__(256) void k_sim(const float* __restrict__ testM,
                                             const float* __restrict__ proto,
                                             const float* __restrict__ W2,
                                             float* __restrict__ sim) {
    int bq = blockIdx.x;
    int b = bq / (TQN / 32), q0 = (bq % (TQN / 32)) * 32;
    __shared__ float st[32][129];
    __shared__ float sp[64][129];
    int t = threadIdx.x;
    int qi = (t >> 4) * 2;      // 0..30
    int ni = (t & 15) * 4;      // 0..60
    float acc[2][4] = {};
    for (int kc = 0; kc < DD; kc += 128) {
        for (int i = t; i < 32 * 32; i += 256) {      // 32 rows x 32 float4
            int row = i >> 5, c4 = i & 31;
            float4 v = *reinterpret_cast<const float4*>(
                &testM[((size_t)b * TQN + q0 + row) * DD + kc + c4 * 4]);
            st[row][c4 * 4 + 0] = v.x; st[row][c4 * 4 + 1] = v.y;
            st[row][c4 * 4 + 2] = v.z; st[row][c4 * 4 + 3] = v.w;
        }
        for (int i = t; i < 64 * 32; i += 256) {      // 64 rows x 32 float4
            int row = i >> 5, c4 = i & 31;
            float4 v = *reinterpret_cast<const float4*>(
                &proto[((size_t)b * NTT + row) * DD + kc + c4 * 4]);
            sp[row][c4 * 4 + 0] = v.x; sp[row][c4 * 4 + 1] = v.y;
            sp[row][c4 * 4 + 2] = v.z; sp[row][c4 * 4 + 3] = v.w;
        }
        __syncthreads();
#pragma unroll 4
        for (int k = 0; k < 128; ++k) {
            float t0 = st[qi][k], t1 = st[qi + 1][k];
            float p0 = sp[ni][k], p1 = sp[ni + 1][k], p2 = sp[ni + 2][k], p3 = sp[ni + 3][k];
            acc[0][0] += t0 * p0; acc[0][1] += t0 * p1; acc[0][2] += t0 * p2; acc[0][3] += t0 * p3;
            acc[1][0] += t1 * p0; acc[1][1] += t1 * p1; acc[1][2] += t1 * p2; acc[1][3] += t1 * p3;
        }
        __syncthreads();
    }
#pragma unroll
    for (int iq = 0; iq < 2; ++iq) {
        int q = q0 + qi + iq;
        float w = W2[b * TQN + q];
        float4 o;
        o.x = acc[iq][0] * w; o.y = acc[iq][1] * w; o.z = acc[iq][2] * w; o.w = acc[iq][3] * w;
        *reinterpret_cast<float4*>(&sim[((size_t)b * TQN + q) * NTT + ni]) = o;
    }
}

// ---------------------------------------------------------------------------
extern "C" void kernel_launch(void* const* d_in, const int* in_sizes, int n_in,
                              void* d_out, int out_size, void* d_ws, size_t ws_size,
                              hipStream_t stream) {
    const float* reps = (const float*)d_in[0];
    const float* sup  = (const float*)d_in[1];
    // d_in[2], d_in[3] masks: all-ones, unused by the reference math
    const float* tgt  = (const float*)d_in[4];
    const float* l1w1 = (const float*)d_in[5];
    const float* l1b1 = (const float*)d_in[6];
    const float* l1w2 = (const float*)d_in[7];
    const float* l1b2 = (const float*)d_in[8];
    const float* l2w1 = (const float*)d_in[9];
    const float* l2b1 = (const float*)d_in[10];
    const float* l2w2 = (const float*)d_in[11];
    const float* l2b2 = (const float*)d_in[12];
    const float* fw1  = (const float*)d_in[13];
    const float* fb1  = (const float*)d_in[14];
    const float* fw2  = (const float*)d_in[15];
    const float* fb2  = (const float*)d_in[16];

    float* out    = (float*)d_out;
    float* simO   = out;                                  // (B,TQ,NT)
    float* protoO = out + (size_t)BB * TQN * NTT;         // (B,NT,D)

    float* w = (float*)d_ws;
    float* testM = w; w += (size_t)BB * TQN * DD;         // 6291456
    float* U     = w; w += (size_t)BB * SS * TQN;         // 131072
    float* Umax  = w; w += 64;
    float* Umin  = w; w += 64;
    float* Usum  = w; w += 64;
    float* cmaxp = w; w += 64;
    float* cminp = w; w += 64;
    float* csump = w; w += 64;
    float* xmax  = w; w += BB * NKK;
    float* xmean = w; w += BB * NKK;
    float* h1    = w; w += BB * 2 * MID1;
    float* W1    = w; w += BB * NKK;
    float* ymax  = w; w += BB * TQN;
    float* ymean = w; w += BB * TQN;
    float* h2    = w; w += BB * 2 * MID2;
    float* W2    = w; w += BB * TQN;

    k_mean<<<BB * TQN * DD / 4 / 256, 256, 0, stream>>>((const float4*)reps, (float4*)testM);
    k_u<<<BB * TQN, 192, 0, stream>>>((const float4*)testM, (const float4*)sup, U);
    k_stats<<<BB * SS, 256, 0, stream>>>(U, tgt, Umax, Umin, Usum, cmaxp, cminp, csump);
    k_rowfeat<<<BB * NKK / 256, 256, 0, stream>>>(tgt, Umax, Umin, Usum, xmax, xmean);
    k_mlp1_h<<<BB, 256, 0, stream>>>(xmax, xmean, l1w1, l1b1, h1);
    k_w1<<<BB, 256, 0, stream>>>(h1, l1w2, l1b2, fw1, fb1, fw2, fb2, W1);
    k_colfeat<<<BB * TQN / 256, 256, 0, stream>>>(U, cmaxp, cminp, csump, ymax, ymean);
    k_mlp2_h<<<BB, 512, 0, stream>>>(ymax, ymean, l2w1, l2b1, h2);
    k_w2<<<BB, 256, 0, stream>>>(h2, l2w2, l2b2, fw1, fb1, fw2, fb2, W2);
    k_proto<<<BB * NTT, 256, 0, stream>>>(W1, tgt, sup, protoO);
    k_sim<<<BB * (TQN / 32), 256, 0, stream>>>(testM, protoO, W2, simO);
}

// Round 2
// 609.539 us; speedup vs baseline: 1.3454x; 1.3454x over previous
//
#include <hip/hip_runtime.h>
#include <hip/hip_bf16.h>
#include <float.h>
#include <math.h>

// dims
#define BB   4
#define SS   16
#define TQN  2048
#define DD   768
#define NTT  64
#define NKK  1024     // SS*NTT
#define MID1 204
#define MID2 409

// ---------------------------------------------------------------------------
// K1: test = mean over s of test_reps  (the HBM-bound pass: 403 MB read)
// ---------------------------------------------------------------------------
__global__ __launch_bounds__(256) void k_mean(const float4* __restrict__ reps,
                                              float4* __restrict__ testM) {
    const int QD4 = TQN * DD / 4;                 // 393216 float4 per (b, s)
    int id = blockIdx.x * 256 + threadIdx.x;      // [0, BB*QD4)
    int b = id / QD4, rem = id - b * QD4;
    const float4* base = reps + (size_t)b * SS * QD4 + rem;
    float4 acc = {0.f, 0.f, 0.f, 0.f};
#pragma unroll
    for (int s = 0; s < SS; ++s) {
        float4 v = base[(size_t)s * QD4];
        acc.x += v.x; acc.y += v.y; acc.z += v.z; acc.w += v.w;
    }
    const float inv = 1.f / SS;
    acc.x *= inv; acc.y *= inv; acc.z *= inv; acc.w *= inv;
    testM[(size_t)b * QD4 + rem] = acc;
}

// ---------------------------------------------------------------------------
// K2: U[b,s,q] = support_reps[b,s,:] . testM[b,q,:]
// ---------------------------------------------------------------------------
__global__ __launch_bounds__(192) void k_u(const float4* __restrict__ testM,
                                           const float4* __restrict__ sup,
                                           float* __restrict__ U) {
    int b = blockIdx.x / TQN, q = blockIdx.x % TQN;
    int t = threadIdx.x;                          // 0..191, each owns 4 d's
    float4 tv = testM[((size_t)b * TQN + q) * (DD / 4) + t];
    float part[SS];
#pragma unroll
    for (int s = 0; s < SS; ++s) {
        float4 sv = sup[((size_t)b * SS + s) * (DD / 4) + t];
        part[s] = tv.x * sv.x + tv.y * sv.y + tv.z * sv.z + tv.w * sv.w;
    }
    __shared__ float rbuf[3][SS];
    int lane = t & 63, wv = t >> 6;
#pragma unroll
    for (int s = 0; s < SS; ++s) {
        float v = part[s];
        for (int o = 32; o; o >>= 1) v += __shfl_down(v, o, 64);
        if (lane == 0) rbuf[wv][s] = v;
    }
    __syncthreads();
    if (t < SS)
        U[((size_t)b * SS + t) * TQN + q] = rbuf[0][t] + rbuf[1][t] + rbuf[2][t];
}

// ---------------------------------------------------------------------------
// K3: per-(b,s) stats of U over q, and of tgt over n
// ---------------------------------------------------------------------------
__global__ __launch_bounds__(256) void k_stats(const float* __restrict__ U,
                                               const float* __restrict__ tgt,
                                               float* __restrict__ Umax, float* __restrict__ Umin,
                                               float* __restrict__ Usum,
                                               float* __restrict__ cmax, float* __restrict__ cmin,
                                               float* __restrict__ csum) {
    int bs = blockIdx.x, t = threadIdx.x;
    const float* u = U + (size_t)bs * TQN;
    float mx = -FLT_MAX, mn = FLT_MAX, sm = 0.f;
    for (int q = t; q < TQN; q += 256) {
        float v = u[q];
        mx = fmaxf(mx, v); mn = fminf(mn, v); sm += v;
    }
    int lane = t & 63, wv = t >> 6;
    for (int o = 32; o; o >>= 1) {
        mx = fmaxf(mx, __shfl_down(mx, o, 64));
        mn = fminf(mn, __shfl_down(mn, o, 64));
        sm += __shfl_down(sm, o, 64);
    }
    __shared__ float smx[4], smn[4], ssm[4];
    if (lane == 0) { smx[wv] = mx; smn[wv] = mn; ssm[wv] = sm; }
    __syncthreads();
    if (t == 0) {
        Umax[bs] = fmaxf(fmaxf(smx[0], smx[1]), fmaxf(smx[2], smx[3]));
        Umin[bs] = fminf(fminf(smn[0], smn[1]), fminf(smn[2], smn[3]));
        Usum[bs] = ssm[0] + ssm[1] + ssm[2] + ssm[3];
    }
    if (wv == 1) {  // wave 1 handles the 64 tgt values
        float v = tgt[(size_t)bs * NTT + lane];
        float tmx = v, tmn = v, tsm = v;
        for (int o = 32; o; o >>= 1) {
            tmx = fmaxf(tmx, __shfl_down(tmx, o, 64));
            tmn = fminf(tmn, __shfl_down(tmn, o, 64));
            tsm += __shfl_down(tsm, o, 64);
        }
        if (lane == 0) { cmax[bs] = tmx; cmin[bs] = tmn; csum[bs] = tsm; }
    }
}

// ---------------------------------------------------------------------------
// K4: branch-1 row features: xmax/xmean over q for each support row
// ---------------------------------------------------------------------------
__global__ __launch_bounds__(256) void k_rowfeat(const float* __restrict__ tgt,
                                                 const float* __restrict__ Umax,
                                                 const float* __restrict__ Umin,
                                                 const float* __restrict__ Usum,
                                                 float* __restrict__ xmax, float* __restrict__ xmean) {
    int i = blockIdx.x * 256 + threadIdx.x;  // [0, BB*NKK)
    int b = i >> 10, r = i & 1023, s = r >> 6;
    int bs = b * SS + s;
    float c = tgt[i];  // flat (b*16+s)*64+n == i
    xmax[i]  = c > 0.f ? c * Umax[bs] : (c < 0.f ? c * Umin[bs] : 0.f);
    xmean[i] = c * Usum[bs] * (1.f / TQN);
}

// ---------------------------------------------------------------------------
// K5 (generic): hidden layer  h{m,a}[b,j] = relu(x{m,a}[b,:] . w1[:,j] + b1[j])
// grid = BB * JT (JT = ceil(NH/64)); 4 waves split the NIN reduction.
// ---------------------------------------------------------------------------
__global__ __launch_bounds__(256) void k_mlp_h(const float* __restrict__ xm,
                                               const float* __restrict__ xa,
                                               const float* __restrict__ w1,
                                               const float* __restrict__ b1,
                                               float* __restrict__ hm, float* __restrict__ ha,
                                               int NIN, int NH, int JT) {
    int blk = blockIdx.x;
    int b = blk / JT, j0 = (blk % JT) * 64;
    int t = threadIdx.x, lane = t & 63, wv = t >> 6;
    __shared__ float sm[2048], sa[2048];
    for (int i = t; i < NIN; i += 256) { sm[i] = xm[b * NIN + i]; sa[i] = xa[b * NIN + i]; }
    __syncthreads();
    int j = j0 + lane;
    float accm = 0.f, acca = 0.f;
    int rq = NIN >> 2;
    int r0 = wv * rq, r1 = r0 + rq;
    if (j < NH) {
        for (int r = r0; r < r1; ++r) {
            float w = w1[(size_t)r * NH + j];
            accm += sm[r] * w;
            acca += sa[r] * w;
        }
    }
    __shared__ float pm[4][64], pa[4][64];
    pm[wv][lane] = accm; pa[wv][lane] = acca;
    __syncthreads();
    if (t < 64 && j0 + t < NH) {
        float bb_ = b1[j0 + t];
        float m_ = pm[0][t] + pm[1][t] + pm[2][t] + pm[3][t] + bb_;
        float a_ = pa[0][t] + pa[1][t] + pa[2][t] + pa[3][t] + bb_;
        hm[b * NH + j0 + t] = fmaxf(m_, 0.f);
        ha[b * NH + j0 + t] = fmaxf(a_, 0.f);
    }
}

// ---------------------------------------------------------------------------
// K6 (generic): out layer + fuse MLP -> y[b,r] (pre-softmax)
// grid = BB * RT (RT = NOUT/128); 2 j-partitions per output.
// ---------------------------------------------------------------------------
__global__ __launch_bounds__(256) void k_mlp_out(const float* __restrict__ hm,
                                                 const float* __restrict__ ha,
                                                 const float* __restrict__ w2,
                                                 const float* __restrict__ b2,
                                                 const float* __restrict__ fw1, const float* __restrict__ fb1,
                                                 const float* __restrict__ fw2, const float* __restrict__ fb2,
                                                 float* __restrict__ y, int NH, int NOUT, int RT) {
    int blk = blockIdx.x;
    int b = blk / RT, r0 = (blk % RT) * 128;
    int t = threadIdx.x;
    int rl = t & 127, jp = t >> 7;
    __shared__ float shm[512], sha[512];
    for (int i = t; i < NH; i += 256) { shm[i] = hm[b * NH + i]; sha[i] = ha[b * NH + i]; }
    __syncthreads();
    float accm = 0.f, acca = 0.f;
    for (int j = jp; j < NH; j += 2) {
        float w = w2[(size_t)j * NOUT + r0 + rl];
        accm += shm[j] * w; acca += sha[j] * w;
    }
    __shared__ float qm[2][128], qa[2][128];
    qm[jp][rl] = accm; qa[jp][rl] = acca;
    __syncthreads();
    if (t < 128) {
        float bb_ = b2[r0 + t];
        float ym = qm[0][t] + qm[1][t] + bb_;
        float ya = qa[0][t] + qa[1][t] + bb_;
        float z = fmaxf(ya * fw1[0] + ym * fw1[1] + fb1[0], 0.f);
        y[b * NOUT + r0 + t] = z * fw2[0] + fb2[0];
    }
}

// ---------------------------------------------------------------------------
// K7: softmax over row of length N, +1.0
// ---------------------------------------------------------------------------
__global__ __launch_bounds__(256) void k_softmax(const float* __restrict__ y,
                                                 float* __restrict__ W, int N) {
    int b = blockIdx.x, t = threadIdx.x;
    const float* yr = y + (size_t)b * N;
    int lane = t & 63, wv = t >> 6;
    __shared__ float rb[4];
    float mx = -FLT_MAX;
    for (int i = t; i < N; i += 256) mx = fmaxf(mx, yr[i]);
    for (int o = 32; o; o >>= 1) mx = fmaxf(mx, __shfl_down(mx, o, 64));
    if (lane == 0) rb[wv] = mx;
    __syncthreads();
    mx = fmaxf(fmaxf(rb[0], rb[1]), fmaxf(rb[2], rb[3]));
    __syncthreads();
    float sm = 0.f;
    for (int i = t; i < N; i += 256) sm += expf(yr[i] - mx);
    for (int o = 32; o; o >>= 1) sm += __shfl_down(sm, o, 64);
    if (lane == 0) rb[wv] = sm;
    __syncthreads();
    sm = rb[0] + rb[1] + rb[2] + rb[3];
    float inv = 1.f / sm;
    for (int i = t; i < N; i += 256) W[(size_t)b * N + i] = expf(yr[i] - mx) * inv + 1.f;
}

// ---------------------------------------------------------------------------
// K8: branch-2 column features over support rows (factored via cmax/cmin/csum)
// ---------------------------------------------------------------------------
__global__ __launch_bounds__(256) void k_colfeat(const float* __restrict__ U,
                                                 const float* __restrict__ cmax,
                                                 const float* __restrict__ cmin,
                                                 const float* __restrict__ csum,
                                                 float* __restrict__ ymax, float* __restrict__ ymean) {
    int i = blockIdx.x * 256 + threadIdx.x;  // [0, BB*TQN)
    int b = i >> 11, q = i & 2047;
    float vmax = -FLT_MAX, vsum = 0.f;
#pragma unroll
    for (int s = 0; s < SS; ++s) {
        int bs = b * SS + s;
        float u = U[(size_t)bs * TQN + q];
        float pm = u > 0.f ? u * cmax[bs] : (u < 0.f ? u * cmin[bs] : 0.f);
        vmax = fmaxf(vmax, pm);
        vsum += u * csum[bs];
    }
    ymax[i] = vmax;
    ymean[i] = vsum * (1.f / NKK);
}

// ---------------------------------------------------------------------------
// K10: proto[b,n,:] = (sum_s W1[b,s*64+n]*tgt[b,s,n]*sup[b,s,:]) / (count+1e-4)
// ---------------------------------------------------------------------------
__global__ __launch_bounds__(256) void k_proto(const float* __restrict__ W1,
                                               const float* __restrict__ tgt,
                                               const float* __restrict__ sup,
                                               float* __restrict__ proto) {
    int bn = blockIdx.x;           // [0, BB*NTT)
    int b = bn >> 6, n = bn & 63;
    int t = threadIdx.x;
    float a0 = 0.f, a1 = 0.f, a2 = 0.f, cnt = 0.f;
#pragma unroll
    for (int s = 0; s < SS; ++s) {
        float tg = tgt[((size_t)b * SS + s) * NTT + n];
        float coef = W1[b * NKK + s * NTT + n] * tg;
        const float* sv = sup + ((size_t)b * SS + s) * DD;
        a0 += coef * sv[t];
        a1 += coef * sv[t + 256];
        a2 += coef * sv[t + 512];
        cnt += tg;
    }
    float inv = 1.f / (cnt + 1e-4f);
    float* p = proto + (size_t)bn * DD;
    p[t] = a0 * inv; p[t + 256] = a1 * inv; p[t + 512] = a2 * inv;
}

// ---------------------------------------------------------------------------
// K11: sim[b,q,n] = W2[b,q] * (testM[b,q,:] . proto[b,n,:])
// ---------------------------------------------------------------------------
__global__ __launch_bounds__(256) void k_sim(const float* __restrict__ testM,
                                             const float* __restrict__ proto,
                                             const float* __restrict__ W2,
                                             float* __restrict__ sim) {
    int bq = blockIdx.x;
    int b = bq / (TQN / 32), q0 = (bq % (TQN / 32)) * 32;
    __shared__ float st[32][129];
    __shared__ float sp[64][129];
    int t = threadIdx.x;
    int qi = (t >> 4) * 2;      // 0..30
    int ni = (t & 15) * 4;      // 0..60
    float acc[2][4] = {};
    for (int kc = 0; kc < DD; kc += 128) {
        for (int i = t; i < 32 * 32; i += 256) {      // 32 rows x 32 float4
            int row = i >> 5, c4 = i & 31;
            float4 v = *reinterpret_cast<const float4*>(
                &testM[((size_t)b * TQN + q0 + row) * DD + kc + c4 * 4]);
            st[row][c4 * 4 + 0] = v.x; st[row][c4 * 4 + 1] = v.y;
            st[row][c4 * 4 + 2] = v.z; st[row][c4 * 4 + 3] = v.w;
        }
        for (int i = t; i < 64 * 32; i += 256) {      // 64 rows x 32 float4
            int row = i >> 5, c4 = i & 31;
            float4 v = *reinterpret_cast<const float4*>(
                &proto[((size_t)b * NTT + row) * DD + kc + c4 * 4]);
            sp[row][c4 * 4 + 0] = v.x; sp[row][c4 * 4 + 1] = v.y;
            sp[row][c4 * 4 + 2] = v.z; sp[row][c4 * 4 + 3] = v.w;
        }
        __syncthreads();
#pragma unroll 4
        for (int k = 0; k < 128; ++k) {
            float t0 = st[qi][k], t1 = st[qi + 1][k];
            float p0 = sp[ni][k], p1 = sp[ni + 1][k], p2 = sp[ni + 2][k], p3 = sp[ni + 3][k];
            acc[0][0] += t0 * p0; acc[0][1] += t0 * p1; acc[0][2] += t0 * p2; acc[0][3] += t0 * p3;
            acc[1][0] += t1 * p0; acc[1][1] += t1 * p1; acc[1][2] += t1 * p2; acc[1][3] += t1 * p3;
        }
        __syncthreads();
    }
#pragma unroll
    for (int iq = 0; iq < 2; ++iq) {
        int q = q0 + qi + iq;
        float w = W2[b * TQN + q];
        float4 o;
        o.x = acc[iq][0] * w; o.y = acc[iq][1] * w; o.z = acc[iq][2] * w; o.w = acc[iq][3] * w;
        *reinterpret_cast<float4*>(&sim[((size_t)b * TQN + q) * NTT + ni]) = o;
    }
}

// ---------------------------------------------------------------------------
extern "C" void kernel_launch(void* const* d_in, const int* in_sizes, int n_in,
                              void* d_out, int out_size, void* d_ws, size_t ws_size,
                              hipStream_t stream) {
    const float* reps = (const float*)d_in[0];
    const float* sup  = (const float*)d_in[1];
    const float* tgt  = (const float*)d_in[4];
    const float* l1w1 = (const float*)d_in[5];
    const float* l1b1 = (const float*)d_in[6];
    const float* l1w2 = (const float*)d_in[7];
    const float* l1b2 = (const float*)d_in[8];
    const float* l2w1 = (const float*)d_in[9];
    const float* l2b1 = (const float*)d_in[10];
    const float* l2w2 = (const float*)d_in[11];
    const float* l2b2 = (const float*)d_in[12];
    const float* fw1  = (const float*)d_in[13];
    const float* fb1  = (const float*)d_in[14];
    const float* fw2  = (const float*)d_in[15];
    const float* fb2  = (const float*)d_in[16];

    float* out    = (float*)d_out;
    float* simO   = out;                                  // (B,TQ,NT)
    float* protoO = out + (size_t)BB * TQN * NTT;         // (B,NT,D)

    float* w = (float*)d_ws;
    float* testM = w; w += (size_t)BB * TQN * DD;         // 6291456
    float* U     = w; w += (size_t)BB * SS * TQN;         // 131072
    float* Umax  = w; w += 64;
    float* Umin  = w; w += 64;
    float* Usum  = w; w += 64;
    float* cmaxp = w; w += 64;
    float* cminp = w; w += 64;
    float* csump = w; w += 64;
    float* xmax  = w; w += BB * NKK;
    float* xmean = w; w += BB * NKK;
    float* h1m   = w; w += BB * MID1;
    float* h1a   = w; w += BB * MID1;
    float* y1    = w; w += BB * NKK;
    float* W1    = w; w += BB * NKK;
    float* ymax  = w; w += BB * TQN;
    float* ymean = w; w += BB * TQN;
    float* h2m   = w; w += BB * MID2;
    float* h2a   = w; w += BB * MID2;
    float* y2    = w; w += BB * TQN;
    float* W2    = w; w += BB * TQN;

    k_mean<<<BB * TQN * DD / 4 / 256, 256, 0, stream>>>((const float4*)reps, (float4*)testM);
    k_u<<<BB * TQN, 192, 0, stream>>>((const float4*)testM, (const float4*)sup, U);
    k_stats<<<BB * SS, 256, 0, stream>>>(U, tgt, Umax, Umin, Usum, cmaxp, cminp, csump);
    k_rowfeat<<<BB * NKK / 256, 256, 0, stream>>>(tgt, Umax, Umin, Usum, xmax, xmean);
    // branch 1 MLPs:   NIN=1024, NH=204 (JT=4);  NOUT=1024 (RT=8)
    k_mlp_h<<<BB * 4, 256, 0, stream>>>(xmax, xmean, l1w1, l1b1, h1m, h1a, NKK, MID1, 4);
    k_mlp_out<<<BB * 8, 256, 0, stream>>>(h1m, h1a, l1w2, l1b2, fw1, fb1, fw2, fb2, y1, MID1, NKK, 8);
    k_softmax<<<BB, 256, 0, stream>>>(y1, W1, NKK);
    // branch 2
    k_colfeat<<<BB * TQN / 256, 256, 0, stream>>>(U, cmaxp, cminp, csump, ymax, ymean);
    k_mlp_h<<<BB * 7, 256, 0, stream>>>(ymax, ymean, l2w1, l2b1, h2m, h2a, TQN, MID2, 7);
    k_mlp_out<<<BB * 16, 256, 0, stream>>>(h2m, h2a, l2w2, l2b2, fw1, fb1, fw2, fb2, y2, MID2, TQN, 16);
    k_softmax<<<BB, 256, 0, stream>>>(y2, W2, TQN);
    // outputs
    k_proto<<<BB * NTT, 256, 0, stream>>>(W1, tgt, sup, protoO);
    k_sim<<<BB * (TQN / 32), 256, 0, stream>>>(testM, protoO, W2, simO);
}

// Round 4
// 365.188 us; speedup vs baseline: 2.2456x; 1.6691x over previous
//
#include <hip/hip_runtime.h>
#include <hip/hip_bf16.h>
#include <float.h>
#include <math.h>

// dims
#define BB   4
#define SS   16
#define TQN  2048
#define DD   768
#define NTT  64
#define NKK  1024     // SS*NTT
#define MID1 204
#define MID2 409

typedef float nt_f4 __attribute__((ext_vector_type(4)));  // native vec for nontemporal builtin

// ---------------------------------------------------------------------------
// K1: test = mean over s of test_reps  (HBM floor: 403 MB read, ~64 us)
// Nontemporal reads: reps is single-use; keep L2 for testM (reused by k_u/k_sim)
// ---------------------------------------------------------------------------
__global__ __launch_bounds__(256) void k_mean(const nt_f4* __restrict__ reps,
                                              nt_f4* __restrict__ testM) {
    const int QD4 = TQN * DD / 4;                 // 393216 float4 per (b, s)
    int id = blockIdx.x * 256 + threadIdx.x;      // [0, BB*QD4)
    int b = id / QD4, rem = id - b * QD4;
    const nt_f4* base = reps + (size_t)b * SS * QD4 + rem;
    nt_f4 acc = {0.f, 0.f, 0.f, 0.f};
#pragma unroll
    for (int s = 0; s < SS; ++s) {
        nt_f4 v = __builtin_nontemporal_load(&base[(size_t)s * QD4]);
        acc += v;
    }
    acc *= (1.f / SS);
    testM[(size_t)b * QD4 + rem] = acc;
}

// ---------------------------------------------------------------------------
// K2: U[b,s,q] = support_reps[b,s,:] . testM[b,q,:]
// ---------------------------------------------------------------------------
__global__ __launch_bounds__(192) void k_u(const float4* __restrict__ testM,
                                           const float4* __restrict__ sup,
                                           float* __restrict__ U) {
    int b = blockIdx.x / TQN, q = blockIdx.x % TQN;
    int t = threadIdx.x;                          // 0..191, each owns 4 d's
    float4 tv = testM[((size_t)b * TQN + q) * (DD / 4) + t];
    float part[SS];
#pragma unroll
    for (int s = 0; s < SS; ++s) {
        float4 sv = sup[((size_t)b * SS + s) * (DD / 4) + t];
        part[s] = tv.x * sv.x + tv.y * sv.y + tv.z * sv.z + tv.w * sv.w;
    }
    __shared__ float rbuf[3][SS];
    int lane = t & 63, wv = t >> 6;
#pragma unroll
    for (int s = 0; s < SS; ++s) {
        float v = part[s];
        for (int o = 32; o; o >>= 1) v += __shfl_down(v, o, 64);
        if (lane == 0) rbuf[wv][s] = v;
    }
    __syncthreads();
    if (t < SS)
        U[((size_t)b * SS + t) * TQN + q] = rbuf[0][t] + rbuf[1][t] + rbuf[2][t];
}

// ---------------------------------------------------------------------------
// K3: per-(b,s) stats of U over q, and of tgt over n
// ---------------------------------------------------------------------------
__global__ __launch_bounds__(256) void k_stats(const float* __restrict__ U,
                                               const float* __restrict__ tgt,
                                               float* __restrict__ Umax, float* __restrict__ Umin,
                                               float* __restrict__ Usum,
                                               float* __restrict__ cmax, float* __restrict__ cmin,
                                               float* __restrict__ csum) {
    int bs = blockIdx.x, t = threadIdx.x;
    const float* u = U + (size_t)bs * TQN;
    float mx = -FLT_MAX, mn = FLT_MAX, sm = 0.f;
    for (int q = t; q < TQN; q += 256) {
        float v = u[q];
        mx = fmaxf(mx, v); mn = fminf(mn, v); sm += v;
    }
    int lane = t & 63, wv = t >> 6;
    for (int o = 32; o; o >>= 1) {
        mx = fmaxf(mx, __shfl_down(mx, o, 64));
        mn = fminf(mn, __shfl_down(mn, o, 64));
        sm += __shfl_down(sm, o, 64);
    }
    __shared__ float smx[4], smn[4], ssm[4];
    if (lane == 0) { smx[wv] = mx; smn[wv] = mn; ssm[wv] = sm; }
    __syncthreads();
    if (t == 0) {
        Umax[bs] = fmaxf(fmaxf(smx[0], smx[1]), fmaxf(smx[2], smx[3]));
        Umin[bs] = fminf(fminf(smn[0], smn[1]), fminf(smn[2], smn[3]));
        Usum[bs] = ssm[0] + ssm[1] + ssm[2] + ssm[3];
    }
    if (wv == 1) {  // wave 1 handles the 64 tgt values
        float v = tgt[(size_t)bs * NTT + lane];
        float tmx = v, tmn = v, tsm = v;
        for (int o = 32; o; o >>= 1) {
            tmx = fmaxf(tmx, __shfl_down(tmx, o, 64));
            tmn = fminf(tmn, __shfl_down(tmn, o, 64));
            tsm += __shfl_down(tsm, o, 64);
        }
        if (lane == 0) { cmax[bs] = tmx; cmin[bs] = tmn; csum[bs] = tsm; }
    }
}

// ---------------------------------------------------------------------------
// K4: MLP1 hidden, with row-features computed in the prologue.
// x_m[r] = c>0 ? c*Umax : c<0 ? c*Umin : 0 ;  x_a[r] = c*Usum/TQN ; c=tgt[b,r]
// grid = BB*4 ; 4 waves split the 1024-deep reduction; lanes own 64 j's.
// ---------------------------------------------------------------------------
__global__ __launch_bounds__(256) void k_mlp1_h(const float* __restrict__ tgt,
                                                const float* __restrict__ Umax,
                                                const float* __restrict__ Umin,
                                                const float* __restrict__ Usum,
                                                const float* __restrict__ w1,
                                                const float* __restrict__ b1,
                                                float* __restrict__ hm, float* __restrict__ ha) {
    const int JT = 4;
    int blk = blockIdx.x;
    int b = blk / JT, j0 = (blk % JT) * 64;
    int t = threadIdx.x, lane = t & 63, wv = t >> 6;
    __shared__ float sm[NKK], sa[NKK];
    for (int i = t; i < NKK; i += 256) {
        int bs = b * SS + (i >> 6);
        float c = tgt[b * NKK + i];
        sm[i] = c > 0.f ? c * Umax[bs] : (c < 0.f ? c * Umin[bs] : 0.f);
        sa[i] = c * Usum[bs] * (1.f / TQN);
    }
    __syncthreads();
    int j = j0 + lane;
    float accm = 0.f, acca = 0.f;
    int r0 = wv * (NKK / 4), r1 = r0 + (NKK / 4);
    if (j < MID1) {
        for (int r = r0; r < r1; ++r) {
            float w = w1[(size_t)r * MID1 + j];
            accm += sm[r] * w;
            acca += sa[r] * w;
        }
    }
    __shared__ float pm[4][64], pa[4][64];
    pm[wv][lane] = accm; pa[wv][lane] = acca;
    __syncthreads();
    if (t < 64 && j0 + t < MID1) {
        float bb_ = b1[j0 + t];
        float m_ = pm[0][t] + pm[1][t] + pm[2][t] + pm[3][t] + bb_;
        float a_ = pa[0][t] + pa[1][t] + pa[2][t] + pa[3][t] + bb_;
        hm[b * MID1 + j0 + t] = fmaxf(m_, 0.f);
        ha[b * MID1 + j0 + t] = fmaxf(a_, 0.f);
    }
}

// ---------------------------------------------------------------------------
// K5: MLP2 hidden, with column-features computed in the prologue.
// y_m[q] = max_s (u>0? u*cmax : u<0? u*cmin : 0) ; y_a[q] = sum_s u*csum /NKK
// grid = BB*7 ; 4 waves split the 2048-deep reduction; lanes own 64 j's.
// ---------------------------------------------------------------------------
__global__ __launch_bounds__(256) void k_mlp2_h(const float* __restrict__ U,
                                                const float* __restrict__ cmax,
                                                const float* __restrict__ cmin,
                                                const float* __restrict__ csum,
                                                const float* __restrict__ w1,
                                                const float* __restrict__ b1,
                                                float* __restrict__ hm, float* __restrict__ ha) {
    const int JT = 7;
    int blk = blockIdx.x;
    int b = blk / JT, j0 = (blk % JT) * 64;
    int t = threadIdx.x, lane = t & 63, wv = t >> 6;
    __shared__ float sm[TQN], sa[TQN];
    for (int i = t; i < TQN; i += 256) {
        float vmax = -FLT_MAX, vsum = 0.f;
#pragma unroll
        for (int s = 0; s < SS; ++s) {
            int bs = b * SS + s;
            float u = U[(size_t)bs * TQN + i];
            float pm_ = u > 0.f ? u * cmax[bs] : (u < 0.f ? u * cmin[bs] : 0.f);
            vmax = fmaxf(vmax, pm_);
            vsum += u * csum[bs];
        }
        sm[i] = vmax;
        sa[i] = vsum * (1.f / NKK);
    }
    __syncthreads();
    int j = j0 + lane;
    float accm = 0.f, acca = 0.f;
    int r0 = wv * (TQN / 4), r1 = r0 + (TQN / 4);
    if (j < MID2) {
        for (int r = r0; r < r1; ++r) {
            float w = w1[(size_t)r * MID2 + j];
            accm += sm[r] * w;
            acca += sa[r] * w;
        }
    }
    __shared__ float pm[4][64], pa[4][64];
    pm[wv][lane] = accm; pa[wv][lane] = acca;
    __syncthreads();
    if (t < 64 && j0 + t < MID2) {
        float bb_ = b1[j0 + t];
        float m_ = pm[0][t] + pm[1][t] + pm[2][t] + pm[3][t] + bb_;
        float a_ = pa[0][t] + pa[1][t] + pa[2][t] + pa[3][t] + bb_;
        hm[b * MID2 + j0 + t] = fmaxf(m_, 0.f);
        ha[b * MID2 + j0 + t] = fmaxf(a_, 0.f);
    }
}

// ---------------------------------------------------------------------------
// K6 (generic): out layer + fuse MLP -> y[b,r] (pre-softmax)
// grid = BB * RT (RT = NOUT/128); 2 j-partitions per output.
// ---------------------------------------------------------------------------
__global__ __launch_bounds__(256) void k_mlp_out(const float* __restrict__ hm,
                                                 const float* __restrict__ ha,
                                                 const float* __restrict__ w2,
                                                 const float* __restrict__ b2,
                                                 const float* __restrict__ fw1, const float* __restrict__ fb1,
                                                 const float* __restrict__ fw2, const float* __restrict__ fb2,
                                                 float* __restrict__ y, int NH, int NOUT, int RT) {
    int blk = blockIdx.x;
    int b = blk / RT, r0 = (blk % RT) * 128;
    int t = threadIdx.x;
    int rl = t & 127, jp = t >> 7;
    __shared__ float shm[512], sha[512];
    for (int i = t; i < NH; i += 256) { shm[i] = hm[b * NH + i]; sha[i] = ha[b * NH + i]; }
    __syncthreads();
    float accm = 0.f, acca = 0.f;
    for (int j = jp; j < NH; j += 2) {
        float w = w2[(size_t)j * NOUT + r0 + rl];
        accm += shm[j] * w; acca += sha[j] * w;
    }
    __shared__ float qm[2][128], qa[2][128];
    qm[jp][rl] = accm; qa[jp][rl] = acca;
    __syncthreads();
    if (t < 128) {
        float bb_ = b2[r0 + t];
        float ym = qm[0][t] + qm[1][t] + bb_;
        float ya = qa[0][t] + qa[1][t] + bb_;
        float z = fmaxf(ya * fw1[0] + ym * fw1[1] + fb1[0], 0.f);
        y[b * NOUT + r0 + t] = z * fw2[0] + fb2[0];
    }
}

// ---------------------------------------------------------------------------
// K7: both softmaxes in one launch. blocks 0..3 -> y1 (N=1024), 4..7 -> y2 (2048)
// ---------------------------------------------------------------------------
__global__ __launch_bounds__(256) void k_softmax2(const float* __restrict__ y1,
                                                  float* __restrict__ W1,
                                                  const float* __restrict__ y2,
                                                  float* __restrict__ W2) {
    int blk = blockIdx.x, t = threadIdx.x;
    const float* yr; float* Wr; int N;
    if (blk < BB) { yr = y1 + (size_t)blk * NKK; Wr = W1 + (size_t)blk * NKK; N = NKK; }
    else          { yr = y2 + (size_t)(blk - BB) * TQN; Wr = W2 + (size_t)(blk - BB) * TQN; N = TQN; }
    int lane = t & 63, wv = t >> 6;
    __shared__ float rb[4];
    float mx = -FLT_MAX;
    for (int i = t; i < N; i += 256) mx = fmaxf(mx, yr[i]);
    for (int o = 32; o; o >>= 1) mx = fmaxf(mx, __shfl_down(mx, o, 64));
    if (lane == 0) rb[wv] = mx;
    __syncthreads();
    mx = fmaxf(fmaxf(rb[0], rb[1]), fmaxf(rb[2], rb[3]));
    __syncthreads();
    float sm = 0.f;
    for (int i = t; i < N; i += 256) sm += expf(yr[i] - mx);
    for (int o = 32; o; o >>= 1) sm += __shfl_down(sm, o, 64);
    if (lane == 0) rb[wv] = sm;
    __syncthreads();
    sm = rb[0] + rb[1] + rb[2] + rb[3];
    float inv = 1.f / sm;
    for (int i = t; i < N; i += 256) Wr[i] = expf(yr[i] - mx) * inv + 1.f;
}

// ---------------------------------------------------------------------------
// K8: proto[b,n,:] = (sum_s W1[b,s*64+n]*tgt[b,s,n]*sup[b,s,:]) / (count+1e-4)
// ---------------------------------------------------------------------------
__global__ __launch_bounds__(256) void k_proto(const float* __restrict__ W1,
                                               const float* __restrict__ tgt,
                                               const float* __restrict__ sup,
                                               float* __restrict__ proto) {
    int bn = blockIdx.x;           // [0, BB*NTT)
    int b = bn >> 6, n = bn & 63;
    int t = threadIdx.x;
    float a0 = 0.f, a1 = 0.f, a2 = 0.f, cnt = 0.f;
#pragma unroll
    for (int s = 0; s < SS; ++s) {
        float tg = tgt[((size_t)b * SS + s) * NTT + n];
        float coef = W1[b * NKK + s * NTT + n] * tg;
        const float* sv = sup + ((size_t)b * SS + s) * DD;
        a0 += coef * sv[t];
        a1 += coef * sv[t + 256];
        a2 += coef * sv[t + 512];
        cnt += tg;
    }
    float inv = 1.f / (cnt + 1e-4f);
    float* p = proto + (size_t)bn * DD;
    p[t] = a0 * inv; p[t + 256] = a1 * inv; p[t + 512] = a2 * inv;
}

// ---------------------------------------------------------------------------
// K9: sim[b,q,n] = W2[b,q] * (testM[b,q,:] . proto[b,n,:])
// ---------------------------------------------------------------------------
__global__ __launch_bounds__(256) void k_sim(const float* __restrict__ testM,
                                             const float* __restrict__ proto,
                                             const float* __restrict__ W2,
                                             float* __restrict__ sim) {
    int bq = blockIdx.x;
    int b = bq / (TQN / 32), q0 = (bq % (TQN / 32)) * 32;
    __shared__ float st[32][129];
    __shared__ float sp[64][129];
    int t = threadIdx.x;
    int qi = (t >> 4) * 2;      // 0..30
    int ni = (t & 15) * 4;      // 0..60
    float acc[2][4] = {};
    for (int kc = 0; kc < DD; kc += 128) {
        for (int i = t; i < 32 * 32; i += 256) {      // 32 rows x 32 float4
            int row = i >> 5, c4 = i & 31;
            float4 v = *reinterpret_cast<const float4*>(
                &testM[((size_t)b * TQN + q0 + row) * DD + kc + c4 * 4]);
            st[row][c4 * 4 + 0] = v.x; st[row][c4 * 4 + 1] = v.y;
            st[row][c4 * 4 + 2] = v.z; st[row][c4 * 4 + 3] = v.w;
        }
        for (int i = t; i < 64 * 32; i += 256) {      // 64 rows x 32 float4
            int row = i >> 5, c4 = i & 31;
            float4 v = *reinterpret_cast<const float4*>(
                &proto[((size_t)b * NTT + row) * DD + kc + c4 * 4]);
            sp[row][c4 * 4 + 0] = v.x; sp[row][c4 * 4 + 1] = v.y;
            sp[row][c4 * 4 + 2] = v.z; sp[row][c4 * 4 + 3] = v.w;
        }
        __syncthreads();
#pragma unroll 4
        for (int k = 0; k < 128; ++k) {
            float t0 = st[qi][k], t1 = st[qi + 1][k];
            float p0 = sp[ni][k], p1 = sp[ni + 1][k], p2 = sp[ni + 2][k], p3 = sp[ni + 3][k];
            acc[0][0] += t0 * p0; acc[0][1] += t0 * p1; acc[0][2] += t0 * p2; acc[0][3] += t0 * p3;
            acc[1][0] += t1 * p0; acc[1][1] += t1 * p1; acc[1][2] += t1 * p2; acc[1][3] += t1 * p3;
        }
        __syncthreads();
    }
#pragma unroll
    for (int iq = 0; iq < 2; ++iq) {
        int q = q0 + qi + iq;
        float w = W2[b * TQN + q];
        float4 o;
        o.x = acc[iq][0] * w; o.y = acc[iq][1] * w; o.z = acc[iq][2] * w; o.w = acc[iq][3] * w;
        *reinterpret_cast<float4*>(&sim[((size_t)b * TQN + q) * NTT + ni]) = o;
    }
}

// ---------------------------------------------------------------------------
extern "C" void kernel_launch(void* const* d_in, const int* in_sizes, int n_in,
                              void* d_out, int out_size, void* d_ws, size_t ws_size,
                              hipStream_t stream) {
    const float* reps = (const float*)d_in[0];
    const float* sup  = (const float*)d_in[1];
    const float* tgt  = (const float*)d_in[4];
    const float* l1w1 = (const float*)d_in[5];
    const float* l1b1 = (const float*)d_in[6];
    const float* l1w2 = (const float*)d_in[7];
    const float* l1b2 = (const float*)d_in[8];
    const float* l2w1 = (const float*)d_in[9];
    const float* l2b1 = (const float*)d_in[10];
    const float* l2w2 = (const float*)d_in[11];
    const float* l2b2 = (const float*)d_in[12];
    const float* fw1  = (const float*)d_in[13];
    const float* fb1  = (const float*)d_in[14];
    const float* fw2  = (const float*)d_in[15];
    const float* fb2  = (const float*)d_in[16];

    float* out    = (float*)d_out;
    float* simO   = out;                                  // (B,TQ,NT)
    float* protoO = out + (size_t)BB * TQN * NTT;         // (B,NT,D)

    float* w = (float*)d_ws;
    float* testM = w; w += (size_t)BB * TQN * DD;         // 6291456
    float* U     = w; w += (size_t)BB * SS * TQN;         // 131072
    float* Umax  = w; w += 64;
    float* Umin  = w; w += 64;
    float* Usum  = w; w += 64;
    float* cmaxp = w; w += 64;
    float* cminp = w; w += 64;
    float* csump = w; w += 64;
    float* h1m   = w; w += BB * MID1;
    float* h1a   = w; w += BB * MID1;
    float* y1    = w; w += BB * NKK;
    float* W1    = w; w += BB * NKK;
    float* h2m   = w; w += BB * MID2;
    float* h2a   = w; w += BB * MID2;
    float* y2    = w; w += BB * TQN;
    float* W2    = w; w += BB * TQN;

    k_mean<<<BB * TQN * DD / 4 / 256, 256, 0, stream>>>((const nt_f4*)reps, (nt_f4*)testM);
    k_u<<<BB * TQN, 192, 0, stream>>>((const float4*)testM, (const float4*)sup, U);
    k_stats<<<BB * SS, 256, 0, stream>>>(U, tgt, Umax, Umin, Usum, cmaxp, cminp, csump);
    // branch 1
    k_mlp1_h<<<BB * 4, 256, 0, stream>>>(tgt, Umax, Umin, Usum, l1w1, l1b1, h1m, h1a);
    k_mlp_out<<<BB * 8, 256, 0, stream>>>(h1m, h1a, l1w2, l1b2, fw1, fb1, fw2, fb2, y1, MID1, NKK, 8);
    // branch 2
    k_mlp2_h<<<BB * 7, 256, 0, stream>>>(U, cmaxp, cminp, csump, l2w1, l2b1, h2m, h2a);
    k_mlp_out<<<BB * 16, 256, 0, stream>>>(h2m, h2a, l2w2, l2b2, fw1, fb1, fw2, fb2, y2, MID2, TQN, 16);
    // softmaxes
    k_softmax2<<<2 * BB, 256, 0, stream>>>(y1, W1, y2, W2);
    // outputs
    k_proto<<<BB * NTT, 256, 0, stream>>>(W1, tgt, sup, protoO);
    k_sim<<<BB * (TQN / 32), 256, 0, stream>>>(testM, protoO, W2, simO);
}